// Round 1
// baseline (449.263 us; speedup 1.0000x reference)
//
#include <hip/hip_runtime.h>
#include <hip/hip_bf16.h>

// Shapes (compile-time constants from the reference):
// x: (B=8, A_IN=16, C_IN=4, H=64, W=64) fp32
// W: (C_OUT*A_OUT=256, A_IN=16, 5, 5) fp32
// b: (1,1,8,32) fp32
// out: (B=8, A_OUT=32, C_OUT=8, 64, 64) fp32  -> 8,388,608 floats
//
// conv input t2[n,a,h,w] = tbuf[n*65536 + a*4096 + h*64 + w]
// where tbuf[n*65536 + h1*1024 + w1*16 + a1] = x[b0,a1,ci,h1,w1], n=ci*8+b0
// conv output (n,oc,y,x) contiguous == votes(B,C_IN,h,w,C_OUT,A_OUT) contiguous.

#define EPSF 1e-7f

__global__ __launch_bounds__(256) void k_transpose_x(
    const float* __restrict__ x, float* __restrict__ t) {
  int j = blockIdx.x * 256 + threadIdx.x;        // 2,097,152 total
  int n  = j >> 16;
  int r  = j & 65535;
  int h1 = r >> 10;
  int w1 = (r >> 4) & 63;
  int a1 = r & 15;
  int ci = n >> 3, b0 = n & 7;
  t[j] = x[b0 * 262144 + a1 * 16384 + ci * 4096 + h1 * 64 + w1];
}

__global__ __launch_bounds__(256) void k_transpose_w(
    const float* __restrict__ W, float* __restrict__ Wt) {
  int j = blockIdx.x * 256 + threadIdx.x;        // 102,400 total
  int oc = j / 400;
  int k  = j - oc * 400;
  Wt[k * 256 + oc] = W[j];                       // Wt[k][oc], oc contiguous
}

// One block per (n, y). 4 waves; wave w handles oc in [w*64, w*64+64).
// lane = output x. 64 fp32 accumulators per thread.
__global__ __launch_bounds__(256) void k_conv_votes(
    const float* __restrict__ t, const float* __restrict__ Wt,
    float* __restrict__ votes) {
  __shared__ float lin[16][5][68];
  const int y = blockIdx.x;      // 0..63
  const int n = blockIdx.y;      // 0..31
  const int tid = threadIdx.x;

  // Stage the 5-row input slab (16 ch x 5 rows x 68 padded cols) into LDS.
  for (int e = tid; e < 16 * 5 * 68; e += 256) {
    int a  = e / 340;            // 5*68
    int rr = e - a * 340;
    int ky = rr / 68;
    int xx = rr - ky * 68;
    int row = y + ky - 2;
    int col = xx - 2;
    float v = 0.f;
    if (row >= 0 && row < 64 && col >= 0 && col < 64)
      v = t[n * 65536 + a * 4096 + row * 64 + col];
    lin[a][ky][xx] = v;
  }
  __syncthreads();

  const int lane = tid & 63;
  const int ocg  = __builtin_amdgcn_readfirstlane(tid >> 6);  // wave-uniform

  float acc[64];
#pragma unroll
  for (int j = 0; j < 64; ++j) acc[j] = 0.f;

  const float* __restrict__ wp0 = Wt + ocg * 64;
  for (int a = 0; a < 16; ++a) {
#pragma unroll
    for (int ky = 0; ky < 5; ++ky) {
#pragma unroll
      for (int kx = 0; kx < 5; ++kx) {
        float in = lin[a][ky][lane + kx];
        const float* __restrict__ wp = wp0 + ((a * 5 + ky) * 5 + kx) * 256;
#pragma unroll
        for (int j = 0; j < 64; ++j)
          acc[j] = fmaf(in, wp[j], acc[j]);
      }
    }
  }

  float* __restrict__ vout = votes + n * 1048576 + (ocg * 64) * 4096 + y * 64 + lane;
#pragma unroll
  for (int j = 0; j < 64; ++j)
    vout[j * 4096] = acc[j];
}

// One wave per spatial position (b,h,w). 4 positions per 256-thread block.
// Lane l holds votes elements e = 4l..4l+3 of the (o,a) 256-vector per i:
//   o = l>>3, a0 = (l&7)*4.
__global__ __launch_bounds__(256) void k_routing(
    const float* __restrict__ votes, const float* __restrict__ bias,
    float* __restrict__ out) {
  const int tid  = threadIdx.x;
  const int lane = tid & 63;
  const int p    = blockIdx.x * 4 + (tid >> 6);   // 0..32767
  const int b    = p >> 12;
  const int h    = (p >> 6) & 63;
  const int w    = p & 63;

  const float* vb = votes + (size_t)b * 4194304 + h * 16384 + w * 256 + lane * 4;
  float4 v[4];
#pragma unroll
  for (int i = 0; i < 4; ++i)
    v[i] = *(const float4*)(vb + (size_t)i * 1048576);
  float4 bia = *(const float4*)(bias + lane * 4);

  float logit[4] = {0.f, 0.f, 0.f, 0.f};
  float act[4];

#pragma unroll
  for (int r = 0; r < 3; ++r) {
    // softmax over o (8 groups across lane-xor {8,16,32}) for each i
    float route[4];
#pragma unroll
    for (int i = 0; i < 4; ++i) {
      float m = logit[i];
      m = fmaxf(m, __shfl_xor(m, 8, 64));
      m = fmaxf(m, __shfl_xor(m, 16, 64));
      m = fmaxf(m, __shfl_xor(m, 32, 64));
      float e = __expf(logit[i] - m);
      float s = e;
      s += __shfl_xor(s, 8, 64);
      s += __shfl_xor(s, 16, 64);
      s += __shfl_xor(s, 32, 64);
      route[i] = e / s;
    }
    // preact = sum_i route_i * votes_i + bias   (4 local elements)
    float pr[4] = {bia.x, bia.y, bia.z, bia.w};
#pragma unroll
    for (int i = 0; i < 4; ++i) {
      pr[0] = fmaf(route[i], v[i].x, pr[0]);
      pr[1] = fmaf(route[i], v[i].y, pr[1]);
      pr[2] = fmaf(route[i], v[i].z, pr[2]);
      pr[3] = fmaf(route[i], v[i].w, pr[3]);
    }
    // squash over a (32 elems = 8 lanes x 4, lane-xor {1,2,4})
    float sq = pr[0]*pr[0] + pr[1]*pr[1] + pr[2]*pr[2] + pr[3]*pr[3];
    sq += __shfl_xor(sq, 1, 64);
    sq += __shfl_xor(sq, 2, 64);
    sq += __shfl_xor(sq, 4, 64);
    float scale = sq / (1.f + sq) / sqrtf(sq + EPSF);
#pragma unroll
    for (int j = 0; j < 4; ++j) act[j] = pr[j] * scale;

    if (r < 2) {
      // agreement[i] = sum_a votes_i . act  -> update logits
#pragma unroll
      for (int i = 0; i < 4; ++i) {
        float ag = v[i].x*act[0] + v[i].y*act[1] + v[i].z*act[2] + v[i].w*act[3];
        ag += __shfl_xor(ag, 1, 64);
        ag += __shfl_xor(ag, 2, 64);
        ag += __shfl_xor(ag, 4, 64);
        logit[i] += ag;
      }
    }
  }

  // out[b, a, o, h, w]
  const int o  = lane >> 3;
  const int a0 = (lane & 7) * 4;
  float* ob = out + (size_t)b * 1048576 + (size_t)a0 * 32768 + o * 4096 + h * 64 + w;
#pragma unroll
  for (int j = 0; j < 4; ++j)
    ob[(size_t)j * 32768] = act[j];
}

extern "C" void kernel_launch(void* const* d_in, const int* in_sizes, int n_in,
                              void* d_out, int out_size, void* d_ws, size_t ws_size,
                              hipStream_t stream) {
  const float* x  = (const float*)d_in[0];   // 2,097,152
  const float* W  = (const float*)d_in[1];   // 102,400
  const float* b  = (const float*)d_in[2];   // 256
  float* out = (float*)d_out;                // 8,388,608
  float* ws  = (float*)d_ws;

  float* tbuf  = ws;                          // 2,097,152 floats
  float* Wt    = ws + 2097152;                // 102,400 floats
  float* votes = ws + 2097152 + 102400;       // 33,554,432 floats (128 MB)

  k_transpose_x<<<8192, 256, 0, stream>>>(x, tbuf);
  k_transpose_w<<<400, 256, 0, stream>>>(W, Wt);
  dim3 g(64, 32);
  k_conv_votes<<<g, 256, 0, stream>>>(tbuf, Wt, votes);
  k_routing<<<8192, 256, 0, stream>>>(votes, b, out);
}

// Round 3
// 161.895 us; speedup vs baseline: 2.7750x; 2.7750x over previous
//
#include <hip/hip_runtime.h>
#include <hip/hip_bf16.h>

// Shapes: x(8,16,4,64,64) f32, W(256,16,5,5) f32, b(1,1,8,32) f32
// out(8,32,8,64,64) f32.
//
// Reference reshapes (verified in passing R1):
//   conv input  t2[n,a,h,w] = x[b0, fl&15, ci, fl>>10, (fl>>4)&63],
//     fl = a*4096 + h*64 + w, n = ci*8 + b0   (the transpose+raw-reshape scramble)
//   conv output flat (n,oc,y,x) == routing votes flat (bv,civ,h,w,o,ao)
//     with n = bv*4 + civ (pure flat-index reinterpret; R1-verified).
//
// Conv = implicit GEMM on v_mfma_f32_16x16x32_f16 (measured layouts m89/m120):
//   A[m=lane&15][k=(lane>>4)*8+j], B[k=(lane>>4)*8+j][n=lane&15],
//   D[row=(lane>>4)*4+r][col=lane&15].
// K=400 = 25 taps x 16 atoms -> 13 steps of K=32 (2 taps each; tap 25 = zero
// weight plane, B address clamped -> contributes 0).

typedef _Float16 half8 __attribute__((ext_vector_type(8)));
typedef _Float16 half4v __attribute__((ext_vector_type(4)));
typedef float floatx4 __attribute__((ext_vector_type(4)));

#define EPSF 1e-7f

// th chunk (n, a0h, h, w) holds t2[n, a0h*8+j, h, w] for j=0..7, f16.
__global__ __launch_bounds__(256) void k_pack(const float* __restrict__ x,
                                              _Float16* __restrict__ th) {
  int idx = blockIdx.x * 256 + threadIdx.x;     // 262,144 chunks
  int n   = idx >> 13;
  int a0h = (idx >> 12) & 1;
  int hw  = idx & 4095;
  int ci = n >> 3, b0 = n & 7;
  const float* xb = x + b0 * 262144 + ci * 4096;
  half8 v;
#pragma unroll
  for (int j = 0; j < 8; ++j) {
    int a  = a0h * 8 + j;
    int fl = a * 4096 + hw;
    int h1 = fl >> 10;
    int w1 = (fl >> 4) & 63;
    int a1 = fl & 15;
    v[j] = (_Float16)xb[a1 * 16384 + h1 * 64 + w1];
  }
  *(half8*)(th + (size_t)idx * 8) = v;
}

// W (oc,a,ky,kx) f32 -> Wp (kk=0..25, oc, a) f16; plane kk==25 is zeros.
__global__ __launch_bounds__(256) void k_packw(const float* __restrict__ W,
                                               _Float16* __restrict__ Wp) {
  int id = blockIdx.x * 256 + threadIdx.x;      // 106,496 = 26*4096
  int a  = id & 15;
  int oc = (id >> 4) & 255;
  int kk = id >> 12;
  Wp[id] = (kk < 25) ? (_Float16)W[oc * 400 + a * 25 + kk] : (_Float16)0.0f;
}

// One block per (n,y): M=256 oc x N=64 px, K=400. 4 waves; wave wv owns
// oc in [wv*64, wv*64+64) as 4x4 tiles of 16x16x32 MFMA.
__global__ __launch_bounds__(256) void k_conv(const _Float16* __restrict__ th,
                                              const _Float16* __restrict__ Wp,
                                              _Float16* __restrict__ votes) {
  __shared__ _Float16 lds[5440];                // (a0h=2, row=5, col=68, 8a)
  const int y = blockIdx.x;
  const int n = blockIdx.y;
  const int tid = threadIdx.x;

  for (int c = tid; c < 680; c += 256) {
    int a0h = c / 340;
    int rem = c - a0h * 340;
    int r   = rem / 68;
    int col = rem - r * 68;
    int row = y + r - 2;
    half8 v = {};
    if (col >= 2 && col <= 65 && row >= 0 && row < 64)
      v = *(const half8*)(th + (size_t)(((n * 2 + a0h) * 64 + row) * 64 + (col - 2)) * 8);
    *(half8*)(lds + c * 8) = v;
  }
  __syncthreads();

  const int lane  = tid & 63;
  const int wv    = tid >> 6;
  const int col16 = lane & 15;
  const int quad  = lane >> 4;      // 0..3
  const int t     = quad >> 1;      // tap-within-pair
  const int a0h   = quad & 1;       // atom-half
  const int m0    = wv * 64;

  floatx4 acc[4][4] = {};

  // A: Wp[(2s+t)][m0+oct*16+col16][a0h*8 .. +7]
  const _Float16* wbase = Wp + (size_t)t * 4096 + (m0 + col16) * 16 + a0h * 8;
  half8 af[4], an[4], bf[4];
#pragma unroll
  for (int oct = 0; oct < 4; ++oct)
    af[oct] = *(const half8*)(wbase + oct * 256);

  for (int s = 0; s < 13; ++s) {
    int kkb = 2 * s + t; if (kkb > 24) kkb = 24;   // clamp for zero plane 25
    int ky = kkb / 5;
    int kx = kkb - ky * 5;
    const _Float16* lb = lds + (a0h * 340 + ky * 68 + col16 + kx) * 8;
#pragma unroll
    for (int xt = 0; xt < 4; ++xt)
      bf[xt] = *(const half8*)(lb + xt * 128);
    int sn = (s + 1 < 13) ? (s + 1) : s;
#pragma unroll
    for (int oct = 0; oct < 4; ++oct)
      an[oct] = *(const half8*)(wbase + (size_t)sn * 8192 + oct * 256);
#pragma unroll
    for (int oct = 0; oct < 4; ++oct)
#pragma unroll
      for (int xt = 0; xt < 4; ++xt)
        acc[oct][xt] = __builtin_amdgcn_mfma_f32_16x16x32_f16(
            af[oct], bf[xt], acc[oct][xt], 0, 0, 0);
#pragma unroll
    for (int oct = 0; oct < 4; ++oct) af[oct] = an[oct];
  }

  // D[row=quad*4+r][col=col16] per tile -> votes[n, oc, y, x]
  _Float16* vbase = votes + (size_t)n * 1048576 + y * 64;
#pragma unroll
  for (int oct = 0; oct < 4; ++oct)
#pragma unroll
    for (int xt = 0; xt < 4; ++xt)
#pragma unroll
      for (int r = 0; r < 4; ++r) {
        int oc = m0 + oct * 16 + quad * 4 + r;
        int xx = xt * 16 + col16;
        vbase[(size_t)oc * 4096 + xx] = (_Float16)acc[oct][xt][r];
      }
}

// One wave per routing position; votes read f16, math fp32. (R1-verified logic.)
__global__ __launch_bounds__(256) void k_routing(
    const _Float16* __restrict__ votes, const float* __restrict__ bias,
    float* __restrict__ out) {
  const int tid  = threadIdx.x;
  const int lane = tid & 63;
  const int p    = blockIdx.x * 4 + (tid >> 6);   // 0..32767
  const int b    = p >> 12;
  const int h    = (p >> 6) & 63;
  const int w    = p & 63;

  const _Float16* vb = votes + (size_t)b * 4194304 + h * 16384 + w * 256 + lane * 4;
  float4 v[4];
#pragma unroll
  for (int i = 0; i < 4; ++i) {
    half4v hv = *(const half4v*)(vb + (size_t)i * 1048576);
    v[i] = make_float4((float)hv.x, (float)hv.y, (float)hv.z, (float)hv.w);
  }
  float4 bia = *(const float4*)(bias + lane * 4);

  float logit[4] = {0.f, 0.f, 0.f, 0.f};
  float act[4];

#pragma unroll
  for (int r = 0; r < 3; ++r) {
    float route[4];
#pragma unroll
    for (int i = 0; i < 4; ++i) {
      float m = logit[i];
      m = fmaxf(m, __shfl_xor(m, 8, 64));
      m = fmaxf(m, __shfl_xor(m, 16, 64));
      m = fmaxf(m, __shfl_xor(m, 32, 64));
      float e = __expf(logit[i] - m);
      float s = e;
      s += __shfl_xor(s, 8, 64);
      s += __shfl_xor(s, 16, 64);
      s += __shfl_xor(s, 32, 64);
      route[i] = e / s;
    }
    float pr[4] = {bia.x, bia.y, bia.z, bia.w};
#pragma unroll
    for (int i = 0; i < 4; ++i) {
      pr[0] = fmaf(route[i], v[i].x, pr[0]);
      pr[1] = fmaf(route[i], v[i].y, pr[1]);
      pr[2] = fmaf(route[i], v[i].z, pr[2]);
      pr[3] = fmaf(route[i], v[i].w, pr[3]);
    }
    float sq = pr[0]*pr[0] + pr[1]*pr[1] + pr[2]*pr[2] + pr[3]*pr[3];
    sq += __shfl_xor(sq, 1, 64);
    sq += __shfl_xor(sq, 2, 64);
    sq += __shfl_xor(sq, 4, 64);
    float scale = sq / (1.f + sq) / sqrtf(sq + EPSF);
#pragma unroll
    for (int j = 0; j < 4; ++j) act[j] = pr[j] * scale;

    if (r < 2) {
#pragma unroll
      for (int i = 0; i < 4; ++i) {
        float ag = v[i].x*act[0] + v[i].y*act[1] + v[i].z*act[2] + v[i].w*act[3];
        ag += __shfl_xor(ag, 1, 64);
        ag += __shfl_xor(ag, 2, 64);
        ag += __shfl_xor(ag, 4, 64);
        logit[i] += ag;
      }
    }
  }

  const int o  = lane >> 3;
  const int a0 = (lane & 7) * 4;
  float* ob = out + (size_t)b * 1048576 + (size_t)a0 * 32768 + o * 4096 + h * 64 + w;
#pragma unroll
  for (int j = 0; j < 4; ++j)
    ob[(size_t)j * 32768] = act[j];
}

extern "C" void kernel_launch(void* const* d_in, const int* in_sizes, int n_in,
                              void* d_out, int out_size, void* d_ws, size_t ws_size,
                              hipStream_t stream) {
  const float* x  = (const float*)d_in[0];
  const float* W  = (const float*)d_in[1];
  const float* b  = (const float*)d_in[2];
  float* out = (float*)d_out;

  _Float16* th    = (_Float16*)d_ws;            // 2,097,152 halves (4 MB)
  _Float16* Wp    = th + 2097152;               // 106,496 halves (208 KB)
  _Float16* votes = Wp + 106496;                // 33,554,432 halves (64 MB)

  k_pack<<<1024, 256, 0, stream>>>(x, th);
  k_packw<<<416, 256, 0, stream>>>(W, Wp);
  k_conv<<<dim3(64, 32), 256, 0, stream>>>(th, Wp, votes);
  k_routing<<<8192, 256, 0, stream>>>(votes, b, out);
}

// Round 4
// 142.289 us; speedup vs baseline: 3.1574x; 1.1378x over previous
//
#include <hip/hip_runtime.h>
#include <hip/hip_bf16.h>

// Shapes: x(8,16,4,64,64) f32, W(256,16,5,5) f32, b(1,1,8,32) f32
// out(8,32,8,64,64) f32.
//
// Reference reshapes (verified passing R1/R3):
//   conv input  t2[n,a,h,w] = x[b0, fl&15, ci, fl>>10, (fl>>4)&63],
//     fl = a*4096 + h*64 + w, n = ci*8 + b0
//   votes flat (n,oc,y,x) reinterpreted by routing as (bv,civ,h,w,o,ao)
//     with n = bv*4 + civ.
// Conv = implicit GEMM on v_mfma_f32_16x16x32_f16 (measured layouts m89/m120).

typedef _Float16 half8 __attribute__((ext_vector_type(8)));
typedef _Float16 half4v __attribute__((ext_vector_type(4)));
typedef float floatx4 __attribute__((ext_vector_type(4)));

#define EPSF 1e-7f

// LDS-tile transpose pack: x -> th (n, a0h, h, w, 8a) f16.
// Block = (n, a0h, 16-wide w1 tile). th[(n*8192+a0h*4096+hw)*8+j]
//   = x[b0, hw&15, ci, a0h*32 + j*4 + (hw>>10), (hw>>4)&63].
__global__ __launch_bounds__(256) void k_pack2(const float* __restrict__ x,
                                               _Float16* __restrict__ th) {
  __shared__ float lin[32 * 306 + 18];   // [m=32][a1 pad17][w1 pad18]
  const int bid = blockIdx.x;            // 256 blocks
  const int n   = bid >> 3;
  const int a0h = (bid >> 2) & 1;
  const int W0  = (bid & 3) * 16;
  const int ci = n >> 3, b0 = n & 7;
  const int tid = threadIdx.x;
  const float* xb = x + b0 * 262144 + ci * 4096 + W0;

  // Load 512 rows (a1=16 x m=32) of 16 floats, coalesced float4.
  for (int p = 0; p < 8; ++p) {
    int rr = p * 64 + (tid >> 2);
    int q  = (tid & 3) * 4;
    int a1 = rr >> 5, m = rr & 31;
    float4 v = *(const float4*)(xb + a1 * 16384 + (a0h * 32 + m) * 64 + q);
    float* d = lin + m * 306 + a1 * 18 + q;
    d[0] = v.x; d[1] = v.y; d[2] = v.z; d[3] = v.w;
  }
  __syncthreads();

  // Emit th: per hh pass, thread (w1loc=tid>>4, a1=tid&15) gathers j=0..7,
  // stores one half8 (16B) -> fully coalesced.
  _Float16* tb = th + (size_t)n * 65536 + a0h * 32768 + W0 * 128;
  for (int hh = 0; hh < 4; ++hh) {
    int w1 = tid >> 4, a1 = tid & 15;
    half8 v;
#pragma unroll
    for (int j = 0; j < 8; ++j)
      v[j] = (_Float16)lin[(j * 4 + hh) * 306 + a1 * 18 + w1];
    *(half8*)(tb + hh * 8192 + w1 * 128 + a1 * 8) = v;
  }
}

// W (oc,a,ky,kx) f32 -> Wp (kk=0..25, oc, a) f16; plane kk==25 is zeros.
__global__ __launch_bounds__(256) void k_packw(const float* __restrict__ W,
                                               _Float16* __restrict__ Wp) {
  int id = blockIdx.x * 256 + threadIdx.x;      // 106,496 = 26*4096
  int a  = id & 15;
  int oc = (id >> 4) & 255;
  int kk = id >> 12;
  Wp[id] = (kk < 25) ? (_Float16)W[oc * 400 + a * 25 + kk] : (_Float16)0.0f;
}

// One block per (n,y): M=256 oc x N=64 px, K=400. (unchanged, R3-passing)
__global__ __launch_bounds__(256) void k_conv(const _Float16* __restrict__ th,
                                              const _Float16* __restrict__ Wp,
                                              _Float16* __restrict__ votes) {
  __shared__ _Float16 lds[5440];                // (a0h=2, row=5, col=68, 8a)
  const int y = blockIdx.x;
  const int n = blockIdx.y;
  const int tid = threadIdx.x;

  for (int c = tid; c < 680; c += 256) {
    int a0h = c / 340;
    int rem = c - a0h * 340;
    int r   = rem / 68;
    int col = rem - r * 68;
    int row = y + r - 2;
    half8 v = {};
    if (col >= 2 && col <= 65 && row >= 0 && row < 64)
      v = *(const half8*)(th + (size_t)(((n * 2 + a0h) * 64 + row) * 64 + (col - 2)) * 8);
    *(half8*)(lds + c * 8) = v;
  }
  __syncthreads();

  const int lane  = tid & 63;
  const int wv    = tid >> 6;
  const int col16 = lane & 15;
  const int quad  = lane >> 4;      // 0..3
  const int t     = quad >> 1;      // tap-within-pair
  const int a0h   = quad & 1;       // atom-half
  const int m0    = wv * 64;

  floatx4 acc[4][4] = {};

  const _Float16* wbase = Wp + (size_t)t * 4096 + (m0 + col16) * 16 + a0h * 8;
  half8 af[4], an[4], bf[4];
#pragma unroll
  for (int oct = 0; oct < 4; ++oct)
    af[oct] = *(const half8*)(wbase + oct * 256);

  for (int s = 0; s < 13; ++s) {
    int kkb = 2 * s + t; if (kkb > 24) kkb = 24;   // clamp -> zero plane 25
    int ky = kkb / 5;
    int kx = kkb - ky * 5;
    const _Float16* lb = lds + (a0h * 340 + ky * 68 + col16 + kx) * 8;
#pragma unroll
    for (int xt = 0; xt < 4; ++xt)
      bf[xt] = *(const half8*)(lb + xt * 128);
    int sn = (s + 1 < 13) ? (s + 1) : s;
#pragma unroll
    for (int oct = 0; oct < 4; ++oct)
      an[oct] = *(const half8*)(wbase + (size_t)sn * 8192 + oct * 256);
#pragma unroll
    for (int oct = 0; oct < 4; ++oct)
#pragma unroll
      for (int xt = 0; xt < 4; ++xt)
        acc[oct][xt] = __builtin_amdgcn_mfma_f32_16x16x32_f16(
            af[oct], bf[xt], acc[oct][xt], 0, 0, 0);
#pragma unroll
    for (int oct = 0; oct < 4; ++oct) af[oct] = an[oct];
  }

  _Float16* vbase = votes + (size_t)n * 1048576 + y * 64;
#pragma unroll
  for (int oct = 0; oct < 4; ++oct)
#pragma unroll
    for (int xt = 0; xt < 4; ++xt)
#pragma unroll
      for (int r = 0; r < 4; ++r) {
        int oc = m0 + oct * 16 + quad * 4 + r;
        int xx = xt * 16 + col16;
        vbase[(size_t)oc * 4096 + xx] = (_Float16)acc[oct][xt][r];
      }
}

// Routing v2: block = half-row (bv, h, 32 w's). Wave wv computes 8 positions
// (math identical to R3), stages act in LDS [r=ao*8+o][w pad36], then the
// block writes out coalesced float4 rows (out is contiguous in w for fixed r).
__global__ __launch_bounds__(256) void k_routing2(
    const _Float16* __restrict__ votes, const float* __restrict__ bias,
    float* __restrict__ out) {
  __shared__ float so[256 * 36];        // 36 KB
  const int tid  = threadIdx.x;
  const int lane = tid & 63;
  const int wv   = tid >> 6;
  const int bid  = blockIdx.x;          // 1024
  const int bv = bid >> 7;
  const int h  = (bid >> 1) & 63;
  const int W0 = (bid & 1) * 32;

  float4 bia = *(const float4*)(bias + lane * 4);
  const int o  = lane >> 3;
  const int a0 = (lane & 7) * 4;

  for (int k = 0; k < 8; ++k) {
    const int wl = wv * 8 + k;          // 0..31
    const int w  = W0 + wl;
    const _Float16* vb = votes + (size_t)bv * 4194304 + h * 16384 + w * 256 + lane * 4;
    float4 v[4];
#pragma unroll
    for (int i = 0; i < 4; ++i) {
      half4v hv = *(const half4v*)(vb + (size_t)i * 1048576);
      v[i] = make_float4((float)hv.x, (float)hv.y, (float)hv.z, (float)hv.w);
    }

    float logit[4] = {0.f, 0.f, 0.f, 0.f};
    float act[4];

#pragma unroll
    for (int r = 0; r < 3; ++r) {
      float route[4];
#pragma unroll
      for (int i = 0; i < 4; ++i) {
        float m = logit[i];
        m = fmaxf(m, __shfl_xor(m, 8, 64));
        m = fmaxf(m, __shfl_xor(m, 16, 64));
        m = fmaxf(m, __shfl_xor(m, 32, 64));
        float e = __expf(logit[i] - m);
        float s = e;
        s += __shfl_xor(s, 8, 64);
        s += __shfl_xor(s, 16, 64);
        s += __shfl_xor(s, 32, 64);
        route[i] = e / s;
      }
      float pr[4] = {bia.x, bia.y, bia.z, bia.w};
#pragma unroll
      for (int i = 0; i < 4; ++i) {
        pr[0] = fmaf(route[i], v[i].x, pr[0]);
        pr[1] = fmaf(route[i], v[i].y, pr[1]);
        pr[2] = fmaf(route[i], v[i].z, pr[2]);
        pr[3] = fmaf(route[i], v[i].w, pr[3]);
      }
      float sq = pr[0]*pr[0] + pr[1]*pr[1] + pr[2]*pr[2] + pr[3]*pr[3];
      sq += __shfl_xor(sq, 1, 64);
      sq += __shfl_xor(sq, 2, 64);
      sq += __shfl_xor(sq, 4, 64);
      float scale = sq / (1.f + sq) / sqrtf(sq + EPSF);
#pragma unroll
      for (int j = 0; j < 4; ++j) act[j] = pr[j] * scale;

      if (r < 2) {
#pragma unroll
        for (int i = 0; i < 4; ++i) {
          float ag = v[i].x*act[0] + v[i].y*act[1] + v[i].z*act[2] + v[i].w*act[3];
          ag += __shfl_xor(ag, 1, 64);
          ag += __shfl_xor(ag, 2, 64);
          ag += __shfl_xor(ag, 4, 64);
          logit[i] += ag;
        }
      }
    }

#pragma unroll
    for (int j = 0; j < 4; ++j)
      so[((a0 + j) * 8 + o) * 36 + wl] = act[j];
  }
  __syncthreads();

  // Coalesced writeout: 256 rows x 32 floats.
  float* ob = out + (size_t)bv * 1048576 + h * 64 + W0;
  for (int p = 0; p < 8; ++p) {
    int r  = p * 32 + (tid >> 3);
    int w0 = (tid & 7) * 4;
    float4 v = *(const float4*)(so + r * 36 + w0);
    *(float4*)(ob + (size_t)r * 4096 + w0) = v;
  }
}

extern "C" void kernel_launch(void* const* d_in, const int* in_sizes, int n_in,
                              void* d_out, int out_size, void* d_ws, size_t ws_size,
                              hipStream_t stream) {
  const float* x  = (const float*)d_in[0];
  const float* W  = (const float*)d_in[1];
  const float* b  = (const float*)d_in[2];
  float* out = (float*)d_out;

  _Float16* th    = (_Float16*)d_ws;            // 2,097,152 halves (4 MB)
  _Float16* Wp    = th + 2097152;               // 106,496 halves (208 KB)
  _Float16* votes = Wp + 106496;                // 33,554,432 halves (64 MB)

  k_pack2<<<256, 256, 0, stream>>>(x, th);
  k_packw<<<416, 256, 0, stream>>>(W, Wp);
  k_conv<<<dim3(64, 32), 256, 0, stream>>>(th, Wp, votes);
  k_routing2<<<1024, 256, 0, stream>>>(votes, b, out);
}